// Round 3
// baseline (1937.659 us; speedup 1.0000x reference)
//
#include <hip/hip_runtime.h>
#include <hip/hip_bf16.h>
#include <stdint.h>

#define B_   256
#define T_   512
#define DIN  128
#define DST  128
#define DHID 512

typedef __attribute__((ext_vector_type(8))) short bf16x8;
typedef __attribute__((ext_vector_type(4))) float f32x4;

static __device__ __forceinline__ unsigned short f2bf(float f) {
    union { float f; unsigned int u; } v; v.f = f;
    unsigned int u = v.u;
    unsigned int rounding = 0x7FFFu + ((u >> 16) & 1u);
    u += rounding;
    return (unsigned short)(u >> 16);
}

template <typename T>
static __device__ __forceinline__ void keepreg(T& x) {
    asm volatile("" : "+v"(x));
}

static __device__ __forceinline__ void gload_lds16(const void* g, void* l) {
    __builtin_amdgcn_global_load_lds(
        (const __attribute__((address_space(1))) unsigned int*)g,
        (__attribute__((address_space(3))) unsigned int*)l,
        16, 0, 0);
}

__global__ void cvt_w1t(const float* __restrict__ w1, unsigned short* __restrict__ out) {
    int tid = blockIdx.x * blockDim.x + threadIdx.x;
    int n = tid >> 8;
    int k = tid & 255;
    out[tid] = f2bf(w1[k * DHID + n]);
}

__global__ void cvt_w2t(const float* __restrict__ w2, unsigned short* __restrict__ out) {
    int tid = blockIdx.x * blockDim.x + threadIdx.x;
    int n = tid >> 9;
    int h = tid & 511;
    out[tid] = f2bf(w2[h * DST + n]);
}

__global__ void cvt_x(const float* __restrict__ x, unsigned short* __restrict__ wsx) {
    int tid = blockIdx.x * blockDim.x + threadIdx.x;
    int q  = tid & 15;
    int t  = (tid >> 4) & 511;
    int br = tid >> 13;
    int g  = br >> 4, r = br & 15;
    const float* src = x + ((size_t)br * T_ + t) * DIN + q * 8;
    float4 p = *reinterpret_cast<const float4*>(src);
    float4 s = *reinterpret_cast<const float4*>(src + 4);
    union { bf16x8 v; unsigned short u[8]; } cv;
    cv.u[0] = f2bf(p.x); cv.u[1] = f2bf(p.y); cv.u[2] = f2bf(p.z); cv.u[3] = f2bf(p.w);
    cv.u[4] = f2bf(s.x); cv.u[5] = f2bf(s.y); cv.u[6] = f2bf(s.z); cv.u[7] = f2bf(s.w);
    size_t base = ((size_t)(g * T_ + t)) * 4096 + (size_t)r * 256 + (size_t)((q * 16) ^ ((r & 7) << 4));
    *reinterpret_cast<bf16x8*>((char*)wsx + base) = cv.v;
}

template<bool XLDS>
__global__ __launch_bounds__(512)
__attribute__((amdgpu_waves_per_eu(2, 2)))
void rnn_main(
    const float* __restrict__ x,
    const unsigned short* __restrict__ wsx,
    const unsigned short* __restrict__ w1t,
    const unsigned short* __restrict__ w2t,
    const float* __restrict__ a0,
    const float* __restrict__ b1,
    const float* __restrict__ b2,
    float* __restrict__ out)
{
    __shared__ unsigned short Hs[16 * DHID];
    __shared__ unsigned short a_bf[16 * DST];
    __shared__ unsigned short xbuf[2][16 * DIN];

    const int tid  = threadIdx.x;
    const int lane = tid & 63;
    const int w    = tid >> 6;
    const int bg   = blockIdx.x * 16;
    const int lr   = lane & 15;
    const int lg   = lane >> 4;
    const int swz  = (lr & 7) << 4;

    bf16x8 W1f[4][8];
#pragma unroll
    for (int j = 0; j < 4; ++j) {
        const unsigned short* wr = w1t + (size_t)(w * 64 + j * 16 + lr) * 256 + lg * 8;
#pragma unroll
        for (int kk = 0; kk < 8; ++kk) {
            W1f[j][kk] = *reinterpret_cast<const bf16x8*>(wr + kk * 32);
            keepreg(W1f[j][kk]);
        }
    }
    bf16x8 W2f[8][2];
    {
        const unsigned short* wr = w2t + (size_t)(w * 16 + lr) * 512 + lg * 8;
#pragma unroll
        for (int kk = 0; kk < 8; ++kk) {
            W2f[kk][0] = *reinterpret_cast<const bf16x8*>(wr + kk * 32);
            W2f[kk][1] = *reinterpret_cast<const bf16x8*>(wr + 256 + kk * 32);
            keepreg(W2f[kk][0]);
            keepreg(W2f[kk][1]);
        }
    }

    float a_reg[4];
#pragma unroll
    for (int r = 0; r < 4; ++r)
        a_reg[r] = a0[(size_t)(bg + lg * 4 + r) * DST + w * 16 + lr];
#pragma unroll
    for (int r = 0; r < 4; ++r) {
        int row = lg * 4 + r, col = w * 16 + lr;
        *(unsigned short*)((char*)a_bf + row * 256 + ((col * 2) ^ ((row & 7) << 4))) = f2bf(a_reg[r]);
    }

    float b1v[4];
#pragma unroll
    for (int j = 0; j < 4; ++j) b1v[j] = b1[w * 64 + j * 16 + lr];
    const float b2v = b2[w * 16 + lr];

    if constexpr (XLDS) {
        if (tid < 256) {
            const char* src = (const char*)wsx + (size_t)blockIdx.x * T_ * 4096 + (size_t)tid * 16;
            gload_lds16(src, (char*)&xbuf[0][0] + w * 1024);
        }
    }
    __syncthreads();

    f32x4 acc[4];
#pragma unroll
    for (int j = 0; j < 4; ++j) acc[j] = (f32x4)(0.0f);

    if constexpr (XLDS) {
#pragma unroll
        for (int kk = 0; kk < 4; ++kk) {
            bf16x8 xf = *reinterpret_cast<const bf16x8*>((const char*)&xbuf[0][0] + lr * 256 + ((kk * 64 + lg * 16) ^ swz));
#pragma unroll
            for (int j = 0; j < 4; ++j)
                acc[j] = __builtin_amdgcn_mfma_f32_16x16x32_bf16(xf, W1f[j][kk], acc[j], 0, 0, 0);
        }
    } else {
        const float* xr = x + (size_t)(bg + lr) * (T_ * DIN) + lg * 8;
#pragma unroll
        for (int kk = 0; kk < 4; ++kk) {
            float4 p = *reinterpret_cast<const float4*>(xr + kk * 32);
            float4 q = *reinterpret_cast<const float4*>(xr + kk * 32 + 4);
            union { bf16x8 v; unsigned short u[8]; } cv;
            cv.u[0] = f2bf(p.x); cv.u[1] = f2bf(p.y); cv.u[2] = f2bf(p.z); cv.u[3] = f2bf(p.w);
            cv.u[4] = f2bf(q.x); cv.u[5] = f2bf(q.y); cv.u[6] = f2bf(q.z); cv.u[7] = f2bf(q.w);
#pragma unroll
            for (int j = 0; j < 4; ++j)
                acc[j] = __builtin_amdgcn_mfma_f32_16x16x32_bf16(cv.v, W1f[j][kk], acc[j], 0, 0, 0);
        }
    }

    for (int t = 0; t < T_; ++t) {
        if constexpr (XLDS) {
            if (tid < 256) {
                int tn = (t + 1 < T_) ? t + 1 : T_ - 1;
                const char* src = (const char*)wsx + ((size_t)(blockIdx.x * T_ + tn)) * 4096 + (size_t)tid * 16;
                gload_lds16(src, (char*)&xbuf[(t + 1) & 1][0] + w * 1024);
            }
        }

#pragma unroll
        for (int kk = 0; kk < 4; ++kk) {
            bf16x8 af = *reinterpret_cast<const bf16x8*>((const char*)a_bf + lr * 256 + ((kk * 64 + lg * 16) ^ swz));
#pragma unroll
            for (int j = 0; j < 4; ++j)
                acc[j] = __builtin_amdgcn_mfma_f32_16x16x32_bf16(af, W1f[j][4 + kk], acc[j], 0, 0, 0);
        }

#pragma unroll
        for (int j = 0; j < 4; ++j) {
#pragma unroll
            for (int r = 0; r < 4; ++r) {
                float v = acc[j][r] + b1v[j];
                float e = __expf(2.0f * v);
                float th = 1.0f - 2.0f / (e + 1.0f);
                int row = lg * 4 + r;
                int col = w * 64 + j * 16 + lr;
                *(unsigned short*)((char*)Hs + row * 1024 + ((col * 2) ^ ((row & 7) << 4))) = f2bf(th);
            }
        }
        __syncthreads();

        f32x4 s0 = (f32x4)(0.0f), s1 = (f32x4)(0.0f);
#pragma unroll
        for (int kk = 0; kk < 8; ++kk) {
            bf16x8 h0 = *reinterpret_cast<const bf16x8*>((const char*)Hs + lr * 1024 + ((kk * 64 + lg * 16) ^ swz));
            bf16x8 h1 = *reinterpret_cast<const bf16x8*>((const char*)Hs + lr * 1024 + ((512 + kk * 64 + lg * 16) ^ swz));
            s0 = __builtin_amdgcn_mfma_f32_16x16x32_bf16(h0, W2f[kk][0], s0, 0, 0, 0);
            s1 = __builtin_amdgcn_mfma_f32_16x16x32_bf16(h1, W2f[kk][1], s1, 0, 0, 0);
        }

#pragma unroll
        for (int j = 0; j < 4; ++j) acc[j] = (f32x4)(0.0f);
        if constexpr (XLDS) {
            const char* xb = (const char*)&xbuf[(t + 1) & 1][0];
#pragma unroll
            for (int kk = 0; kk < 4; ++kk) {
                bf16x8 xf = *reinterpret_cast<const bf16x8*>(xb + lr * 256 + ((kk * 64 + lg * 16) ^ swz));
#pragma unroll
                for (int j = 0; j < 4; ++j)
                    acc[j] = __builtin_amdgcn_mfma_f32_16x16x32_bf16(xf, W1f[j][kk], acc[j], 0, 0, 0);
            }
        } else {
            int tn = (t + 1 < T_) ? t + 1 : T_ - 1;
            const float* xr = x + (size_t)(bg + lr) * (T_ * DIN) + (size_t)tn * DIN + lg * 8;
#pragma unroll
            for (int kk = 0; kk < 4; ++kk) {
                float4 p = *reinterpret_cast<const float4*>(xr + kk * 32);
                float4 q = *reinterpret_cast<const float4*>(xr + kk * 32 + 4);
                union { bf16x8 v; unsigned short u[8]; } cv;
                cv.u[0] = f2bf(p.x); cv.u[1] = f2bf(p.y); cv.u[2] = f2bf(p.z); cv.u[3] = f2bf(p.w);
                cv.u[4] = f2bf(q.x); cv.u[5] = f2bf(q.y); cv.u[6] = f2bf(q.z); cv.u[7] = f2bf(q.w);
#pragma unroll
                for (int j = 0; j < 4; ++j)
                    acc[j] = __builtin_amdgcn_mfma_f32_16x16x32_bf16(cv.v, W1f[j][kk], acc[j], 0, 0, 0);
            }
        }

#pragma unroll
        for (int r = 0; r < 4; ++r) {
            float v = a_reg[r] + s0[r] + s1[r] + b2v;
            a_reg[r] = v;
            int row = lg * 4 + r, col = w * 16 + lr;
            *(unsigned short*)((char*)a_bf + row * 256 + ((col * 2) ^ ((row & 7) << 4))) = f2bf(v);
        }
        __syncthreads();
    }

#pragma unroll
    for (int r = 0; r < 4; ++r)
        out[(size_t)(bg + lg * 4 + r) * DST + w * 16 + lr] = a_reg[r];
}

extern "C" void kernel_launch(void* const* d_in, const int* in_sizes, int n_in,
                              void* d_out, int out_size, void* d_ws, size_t ws_size,
                              hipStream_t stream) {
    const float* x  = (const float*)d_in[0];
    const float* a0 = (const float*)d_in[1];
    const float* W1 = (const float*)d_in[2];
    const float* b1 = (const float*)d_in[3];
    const float* W2 = (const float*)d_in[4];
    const float* b2 = (const float*)d_in[5];

    unsigned short* w1t = (unsigned short*)d_ws;
    unsigned short* w2t = w1t + 512 * 256;
    unsigned short* wsx = w2t + 128 * 512;
    const size_t need = (size_t)384 * 1024 + (size_t)B_ * T_ * DIN * 2;

    cvt_w1t<<<512, 256, 0, stream>>>(W1, w1t);
    cvt_w2t<<<256, 256, 0, stream>>>(W2, w2t);

    if (ws_size >= need) {
        cvt_x<<<8192, 256, 0, stream>>>(x, wsx);
        rnn_main<true><<<16, 512, 0, stream>>>(x, wsx, w1t, w2t, a0, b1, b2, (float*)d_out);
    } else {
        rnn_main<false><<<16, 512, 0, stream>>>(x, wsx, w1t, w2t, a0, b1, b2, (float*)d_out);
    }
}